// Round 22
// baseline (696.645 us; speedup 1.0000x reference)
//
#include <hip/hip_runtime.h>
#include <cmath>

#define DEV static __device__ __forceinline__

typedef _Float16 half_t;
typedef _Float16 half2_t __attribute__((ext_vector_type(2)));
typedef _Float16 half4_t __attribute__((ext_vector_type(4)));
typedef _Float16 half8_t __attribute__((ext_vector_type(8)));
typedef float f32x4 __attribute__((ext_vector_type(4)));

// ---------------- FiLM: gamma/beta once ----------------
__global__ void k_film(const float* __restrict__ gf,
                       const float* __restrict__ gW, const float* __restrict__ gb,
                       const float* __restrict__ bW, const float* __restrict__ bb,
                       float* __restrict__ out) {
  int j = threadIdx.x;
  if (j >= 64) return;
  float g = gb[j], b = bb[j];
  for (int k = 0; k < 128; ++k) {
    float v = gf[k];
    g += v * gW[k * 64 + j];
    b += v * bW[k * 64 + j];
  }
  out[j] = 1.0f + g;
  out[64 + j] = b;
}

// ---------------- input projection + FiLM (gamma/beta precomputed) ----------------
__global__ __launch_bounds__(256) void k_input(
    const float* __restrict__ nf, const float* __restrict__ ipW,
    const float* __restrict__ ipb, const float* __restrict__ gbv,
    float* __restrict__ x64, int N) {
  int lane = threadIdx.x & 63;
  int n = blockIdx.x * 4 + (threadIdx.x >> 6);
  if (n >= N) return;
  const float* row = nf + (size_t)n * 5;
  float acc = ipb[lane];
#pragma unroll
  for (int k = 0; k < 5; ++k) acc += row[k] * ipW[k * 64 + lane];
  acc = fmaxf(acc, 0.f);
  x64[(size_t)n * 64 + lane] = acc * gbv[lane] + gbv[64 + lane];
}

// ---------------- CSR build ----------------
__global__ void k_count(const int* __restrict__ dst, int* __restrict__ cnt, int E) {
  int e = blockIdx.x * 256 + threadIdx.x;
  if (e < E) atomicAdd(&cnt[dst[e]], 1);
}

__global__ void k_offsets(const int* __restrict__ cnt, int* __restrict__ start,
                          int* __restrict__ cursor, int N) {
  __shared__ int s[256];
  __shared__ int sbase;
  int tid = threadIdx.x;
  int i = blockIdx.x * 256 + tid;
  int v = (i < N) ? cnt[i] : 0;
  s[tid] = v;
  __syncthreads();
  int x = v;
  for (int d = 1; d < 256; d <<= 1) {
    int t = (tid >= d) ? s[tid - d] : 0;
    __syncthreads();
    x += t;
    s[tid] = x;
    __syncthreads();
  }
  if (tid == 255) sbase = atomicAdd(cursor, x);
  __syncthreads();
  if (i < N) start[i] = sbase + x - v;
}

// scatter permutation only: eid[t] = original edge index (4B scattered writes)
__global__ void k_scatter(const int* __restrict__ dst, const int* __restrict__ start,
                          int* __restrict__ cur, int* __restrict__ eid, int E) {
  int e = blockIdx.x * 256 + threadIdx.x;
  if (e < E) {
    int d = dst[e];
    int p = atomicAdd(&cur[d], 1);
    eid[start[d] + p] = e;
  }
}

// ---------------- edge encoder keyed by CSR position: all writes coalesced ----------------
__global__ __launch_bounds__(256) void k_edgefeat(
    const float* __restrict__ pos, const int* __restrict__ src, const int* __restrict__ dst,
    const int* __restrict__ eid,
    const float* __restrict__ W1, const float* __restrict__ b1,
    const float* __restrict__ W2, const float* __restrict__ b2,
    half_t* __restrict__ ef_csr, int* __restrict__ src_csr, int* __restrict__ dst_csr, int E) {
  __shared__ float sW1[160], sb1[32], sW2[1024], sb2[32];
  for (int i = threadIdx.x; i < 160; i += 256) sW1[i] = W1[i];
  for (int i = threadIdx.x; i < 1024; i += 256) sW2[i] = W2[i];
  if (threadIdx.x < 32) { sb1[threadIdx.x] = b1[threadIdx.x]; sb2[threadIdx.x] = b2[threadIdx.x]; }
  __syncthreads();
  int t = blockIdx.x * 256 + threadIdx.x;
  if (t >= E) return;
  int e = eid[t];
  int s = src[e], d = dst[e];
  src_csr[t] = s;
  dst_csr[t] = d;
  float dx = pos[d * 3 + 0] - pos[s * 3 + 0];
  float dy = pos[d * 3 + 1] - pos[s * 3 + 1];
  float dz = pos[d * 3 + 2] - pos[s * 3 + 2];
  float dist = sqrtf(dx * dx + dy * dy + dz * dz);
  dist = fmaxf(dist, 1e-6f);
  float inv = 1.f / dist;
  float attr[5] = {dx * inv, dy * inv, dz * inv, dist, logf(dist)};
  float h[32];
#pragma unroll
  for (int j = 0; j < 32; ++j) {
    float a = sb1[j];
#pragma unroll
    for (int k = 0; k < 5; ++k) a += attr[k] * sW1[k * 32 + j];
    h[j] = fmaxf(a, 0.f);
  }
  half_t hv[32];
#pragma unroll 4
  for (int j = 0; j < 32; ++j) {
    float a = sb2[j];
#pragma unroll
    for (int k = 0; k < 32; ++k) a += h[k] * sW2[k * 32 + j];
    hv[j] = (half_t)a;
  }
  uint4* ov = (uint4*)(ef_csr + (size_t)t * 32);
  const uint4* iv = (const uint4*)hv;
  ov[0] = iv[0]; ov[1] = iv[1]; ov[2] = iv[2]; ov[3] = iv[3];
}

// ---------------- batched weight prep: MFMA-fragment-ordered f16 packing ----------------
__global__ __launch_bounds__(256) void k_prepAll(
    const float* __restrict__ l0Wl, const float* __restrict__ l0Wr,
    const float* __restrict__ resW, const float* __restrict__ Wl,
    const float* __restrict__ Wr, const float* __restrict__ We,
    const float* __restrict__ opW1,
    half_t* __restrict__ btL0l, half_t* __restrict__ btL0r, half_t* __restrict__ btRes,
    half_t* __restrict__ btWl, half_t* __restrict__ btWr, half_t* __restrict__ wet,
    half_t* __restrict__ btOp1) {
  int m = blockIdx.y;
  const float* W;
  half_t* Bt;
  int K, ncol;
  if (m == 0)      { W = l0Wl; Bt = btL0l; K = 64;  ncol = 256; }
  else if (m == 1) { W = l0Wr; Bt = btL0r; K = 64;  ncol = 256; }
  else if (m == 2) { W = resW; Bt = btRes; K = 64;  ncol = 256; }
  else if (m < 8)  { int i = m - 3;  W = Wl + (size_t)i * 65536; Bt = btWl + (size_t)i * 65536; K = 256; ncol = 256; }
  else if (m < 13) { int i = m - 8;  W = Wr + (size_t)i * 65536; Bt = btWr + (size_t)i * 65536; K = 256; ncol = 256; }
  else if (m < 19) { int i = m - 13; W = We + (size_t)i * 8192;  Bt = wet + (size_t)i * 8192;  K = 32;  ncol = 256; }
  else             { W = opW1; Bt = btOp1; K = 256; ncol = 64; }
  int KS = K >> 5;
  int tot = K * ncol;
  int i = blockIdx.x * 256 + threadIdx.x;
  if (i < tot) {
    int jj = i & 7;
    int lane = (i >> 3) & 63;
    int rest = i >> 9;
    int ks = rest % KS;
    int c16 = rest / KS;
    int k = ks * 32 + (lane >> 4) * 8 + jj;
    int col = c16 * 16 + (lane & 15);
    Bt[i] = (half_t)W[(size_t)k * ncol + col];
  }
}

// ---------------- MFMA f16 GEMM, 64x64 tile per block, fragment-packed B ----------------
template <typename OutT, int NKS>
DEV void gemm_tile(const float* __restrict__ A, const half_t* __restrict__ Bf,
                   const float* __restrict__ bias, OutT* __restrict__ C,
                   int M, int bx, int bcol, int tid) {
  constexpr int K = NKS * 32;
  int w = tid >> 6, lane = tid & 63;
  int r16 = lane & 15, kg = lane >> 4;
  int arow = bx * 64 + w * 16 + r16;
  int arowc = arow < M ? arow : M - 1;
  const float* ap = A + (size_t)arowc * K + kg * 8;
  int c16b = bcol >> 4;
  f32x4 acc[4] = {};
#pragma unroll
  for (int ks = 0; ks < NKS; ++ks) {
    float4 a0 = *(const float4*)(ap + ks * 32);
    float4 a1 = *(const float4*)(ap + ks * 32 + 4);
    half8_t af;
    af[0] = (half_t)a0.x; af[1] = (half_t)a0.y; af[2] = (half_t)a0.z; af[3] = (half_t)a0.w;
    af[4] = (half_t)a1.x; af[5] = (half_t)a1.y; af[6] = (half_t)a1.z; af[7] = (half_t)a1.w;
#pragma unroll
    for (int nt = 0; nt < 4; ++nt) {
      half8_t bf = *(const half8_t*)(Bf + ((((size_t)(c16b + nt) * NKS + ks) * 64 + lane) << 3));
      acc[nt] = __builtin_amdgcn_mfma_f32_16x16x32_f16(af, bf, acc[nt], 0, 0, 0);
    }
  }
  int orow0 = bx * 64 + w * 16 + kg * 4;
#pragma unroll
  for (int nt = 0; nt < 4; ++nt) {
    int gcol = bcol + nt * 16 + r16;
    float bv = bias[gcol];
#pragma unroll
    for (int r = 0; r < 4; ++r) {
      int grow = orow0 + r;
      if (grow < M) C[(size_t)grow * 256 + gcol] = (OutT)(acc[nt][r] + bv);
    }
  }
}

// layers 1..5 (K=256): 1D grid (gx*8), XCD-swizzled (8 tiles of one bx -> same XCD chunk)
__global__ __launch_bounds__(256) void k_gemmL(
    const float* __restrict__ A, const half_t* __restrict__ btl,
    const half_t* __restrict__ btr, const float* __restrict__ bl,
    const float* __restrict__ br, half_t* __restrict__ xl, half_t* __restrict__ xr, int M) {
  int nwg = gridDim.x;
  int cpx = nwg >> 3;
  int orig = blockIdx.x;
  int bid = (orig & 7) * cpx + (orig >> 3);
  int bx = bid >> 3, yt = bid & 7;
  if (yt < 4)
    gemm_tile<half_t, 8>(A, btl, bl, xl, M, bx, yt * 64, threadIdx.x);
  else
    gemm_tile<half_t, 8>(A, btr, br, xr, M, bx, (yt - 4) * 64, threadIdx.x);
}

// layer 0 (K=64)
__global__ __launch_bounds__(256) void k_gemmL0(
    const float* __restrict__ A, const half_t* __restrict__ btl,
    const half_t* __restrict__ btr, const half_t* __restrict__ btres,
    const float* __restrict__ bl, const float* __restrict__ br,
    const float* __restrict__ bres,
    half_t* __restrict__ xl, half_t* __restrict__ xr, float* __restrict__ xres, int M) {
  if (blockIdx.y < 4)
    gemm_tile<half_t, 2>(A, btl, bl, xl, M, blockIdx.x, blockIdx.y * 64, threadIdx.x);
  else if (blockIdx.y < 8)
    gemm_tile<half_t, 2>(A, btr, br, xr, M, blockIdx.x, (blockIdx.y - 4) * 64, threadIdx.x);
  else
    gemm_tile<float, 2>(A, btres, bres, xres, M, blockIdx.x, (blockIdx.y - 8) * 64, threadIdx.x);
}

// ---------------- edge-parallel gate weights: MFMA ef@We (fragment-packed, MLP-hoisted) ----------------
__global__ __launch_bounds__(256) void k_elogits(
    const half_t* __restrict__ ef_csr, const int* __restrict__ src_csr,
    const int* __restrict__ dst_csr, const half_t* __restrict__ xl,
    const half_t* __restrict__ xr, const half_t* __restrict__ wetf,
    const float* __restrict__ att_l, float* __restrict__ logits, int E) {
  int tid = threadIdx.x;
  int w = tid >> 6, lane = tid & 63;
  int r16 = lane & 15, kg = lane >> 4;
  int arow = blockIdx.x * 64 + w * 16 + r16;
  int arowc = arow < E ? arow : E - 1;
  half8_t af = *(const half8_t*)(ef_csr + (size_t)arowc * 32 + kg * 8);
  half8_t bfv[16];
#pragma unroll
  for (int nt = 0; nt < 16; ++nt)
    bfv[nt] = *(const half8_t*)(wetf + (((size_t)nt * 64 + lane) << 3));
  int orow0 = blockIdx.x * 64 + w * 16 + kg * 4;
  int s_[4], d_[4];
#pragma unroll
  for (int r = 0; r < 4; ++r) {
    int tt = orow0 + r;
    tt = tt < E ? tt : E - 1;
    s_[r] = src_csr[tt];
    d_[r] = dst_csr[tt];
  }
  float latt[4][4] = {};  // [head][row]
#pragma unroll
  for (int nt = 0; nt < 16; ++nt) {
    int col = nt * 16 + r16;
    f32x4 dacc = {};
    dacc = __builtin_amdgcn_mfma_f32_16x16x32_f16(af, bfv[nt], dacc, 0, 0, 0);
    float attc = att_l[col];
    float a06 = 0.6f * attc, a04 = 0.4f * attc;
    int hh = nt >> 2;
#pragma unroll
    for (int r = 0; r < 4; ++r) {
      float z = dacc[r] + (float)(xl[(size_t)s_[r] * 256 + col] + xr[(size_t)d_[r] * 256 + col]);
      latt[hh][r] += a06 * z + a04 * fabsf(z);
    }
  }
#pragma unroll
  for (int d = 1; d < 16; d <<= 1) {
#pragma unroll
    for (int hh = 0; hh < 4; ++hh)
#pragma unroll
      for (int r = 0; r < 4; ++r) latt[hh][r] += __shfl_xor(latt[hh][r], d);
  }
  if (r16 == 0) {
#pragma unroll
    for (int r = 0; r < 4; ++r) {
      int tt = orow0 + r;
      if (tt < E) {
        float4 lv = {__expf(latt[0][r]), __expf(latt[1][r]),
                     __expf(latt[2][r]), __expf(latt[3][r])};
        *(float4*)(logits + (size_t)tt * 4) = lv;
      }
    }
  }
}

// ---------------- fused softmax-aggregate + conv_b + LN + relu + residual ----------------
__global__ __launch_bounds__(64) void k_fused(
    const int* __restrict__ start, const int* __restrict__ cnt,
    const int* __restrict__ src_csr, const float* __restrict__ logits,
    const half_t* __restrict__ xl, const float* __restrict__ xprev,
    const float* __restrict__ convb, const float* __restrict__ lng,
    const float* __restrict__ lnb,
    float* __restrict__ xout) {
  int lane = threadIdx.x;
  int n = blockIdx.x;
  int h = lane >> 4, c0 = lane & 15;
  int ch0 = h * 64 + (c0 << 2);
  float4 cb4 = *(const float4*)(convb + ch0);
  float4 g4 = *(const float4*)(lng + ch0);
  float4 b4 = *(const float4*)(lnb + ch0);
  int o0 = start[n];
  int deg = cnt[n];
  int o1 = o0 + deg;
  float s = 0.f;
  float4 a4 = {0.f, 0.f, 0.f, 0.f};

#define LOADG(T0, X0, X1, X2, X3, L0, L1, L2, L3)                                    \
  {                                                                                  \
    int lim = o1 - 1;                                                                \
    int t0_ = (T0) < lim ? (T0) : lim;                                               \
    int t1_ = (T0) + 1 < lim ? (T0) + 1 : lim;                                       \
    int t2_ = (T0) + 2 < lim ? (T0) + 2 : lim;                                       \
    int t3_ = (T0) + 3 < lim ? (T0) + 3 : lim;                                       \
    int S0 = src_csr[t0_], S1 = src_csr[t1_], S2 = src_csr[t2_], S3 = src_csr[t3_];  \
    X0 = *(const half4_t*)(xl + (size_t)S0 * 256 + ch0);                             \
    X1 = *(const half4_t*)(xl + (size_t)S1 * 256 + ch0);                             \
    X2 = *(const half4_t*)(xl + (size_t)S2 * 256 + ch0);                             \
    X3 = *(const half4_t*)(xl + (size_t)S3 * 256 + ch0);                             \
    L0 = logits[(size_t)t0_ * 4 + h];                                                \
    L1 = logits[(size_t)t1_ * 4 + h];                                                \
    L2 = logits[(size_t)t2_ * 4 + h];                                                \
    L3 = logits[(size_t)t3_ * 4 + h];                                                \
  }

#define CVT4(XH, XF)                                                                 \
  float4 XF;                                                                         \
  XF.x = (float)(XH)[0]; XF.y = (float)(XH)[1];                                      \
  XF.z = (float)(XH)[2]; XF.w = (float)(XH)[3];

  if (deg > 0) {
    int nfull = deg >> 2;
    half4_t xh0, xh1, xh2, xh3;
    float l0, l1, l2, l3;
    LOADG(o0, xh0, xh1, xh2, xh3, l0, l1, l2, l3);
    int t0 = o0;
    for (int g = 0; g < nfull; ++g, t0 += 4) {
      half4_t nxh0, nxh1, nxh2, nxh3;
      float nl0, nl1, nl2, nl3;
      LOADG(t0 + 4, nxh0, nxh1, nxh2, nxh3, nl0, nl1, nl2, nl3);
      CVT4(xh0, xf0); CVT4(xh1, xf1); CVT4(xh2, xf2); CVT4(xh3, xf3);
      s += (l0 + l1) + (l2 + l3);
      a4.x += l0 * xf0.x + l1 * xf1.x + l2 * xf2.x + l3 * xf3.x;
      a4.y += l0 * xf0.y + l1 * xf1.y + l2 * xf2.y + l3 * xf3.y;
      a4.z += l0 * xf0.z + l1 * xf1.z + l2 * xf2.z + l3 * xf3.z;
      a4.w += l0 * xf0.w + l1 * xf1.w + l2 * xf2.w + l3 * xf3.w;
      xh0 = nxh0; xh1 = nxh1; xh2 = nxh2; xh3 = nxh3;
      l0 = nl0; l1 = nl1; l2 = nl2; l3 = nl3;
    }
    int r = deg & 3;
    if (r) {
      CVT4(xh0, xf0); CVT4(xh1, xf1); CVT4(xh2, xf2);
      float w0 = l0;
      float w1 = (r > 1) ? l1 : 0.f;
      float w2v = (r > 2) ? l2 : 0.f;
      s += w0 + w1 + w2v;
      a4.x += w0 * xf0.x + w1 * xf1.x + w2v * xf2.x;
      a4.y += w0 * xf0.y + w1 * xf1.y + w2v * xf2.y;
      a4.z += w0 * xf0.z + w1 * xf1.z + w2v * xf2.z;
      a4.w += w0 * xf0.w + w1 * xf1.w + w2v * xf2.w;
    }
  }
#undef CVT4
#undef LOADG

  float inv = (deg > 0) ? 1.f / s : 0.f;
  float4 v4;
  v4.x = a4.x * inv + cb4.x;
  v4.y = a4.y * inv + cb4.y;
  v4.z = a4.z * inv + cb4.z;
  v4.w = a4.w * inv + cb4.w;
  float ssum = v4.x + v4.y + v4.z + v4.w;
  float ssq = v4.x * v4.x + v4.y * v4.y + v4.z * v4.z + v4.w * v4.w;
#pragma unroll
  for (int d = 1; d < 64; d <<= 1) {
    ssum += __shfl_xor(ssum, d);
    ssq += __shfl_xor(ssq, d);
  }
  float mu = ssum * (1.0f / 256.0f);
  float var = ssq * (1.0f / 256.0f) - mu * mu;
  float rstd = rsqrtf(var + 1e-5f);
  float4 xp4 = *(const float4*)(xprev + (size_t)n * 256 + ch0);
  float4 out4;
  out4.x = fmaxf((v4.x - mu) * rstd * g4.x + b4.x, 0.f) + xp4.x;
  out4.y = fmaxf((v4.y - mu) * rstd * g4.y + b4.y, 0.f) + xp4.y;
  out4.z = fmaxf((v4.z - mu) * rstd * g4.z + b4.z, 0.f) + xp4.z;
  out4.w = fmaxf((v4.w - mu) * rstd * g4.w + b4.w, 0.f) + xp4.w;
  *(float4*)(xout + (size_t)n * 256 + ch0) = out4;
}

// ---------------- output projection: MFMA stage1 (256->64, packed B) + stage2 (64->5) ----------------
__global__ __launch_bounds__(256) void k_out2(
    const float* __restrict__ x, const half_t* __restrict__ btOp1,
    const float* __restrict__ b1, const float* __restrict__ W2,
    const float* __restrict__ b2, float* __restrict__ out, int N) {
  int tid = threadIdx.x;
  int w = tid >> 6, lane = tid & 63;
  int r16 = lane & 15, kg = lane >> 4;
  int arow = blockIdx.x * 64 + w * 16 + r16;
  int arowc = arow < N ? arow : N - 1;
  const float* ap = x + (size_t)arowc * 256 + kg * 8;
  half8_t af[8];
#pragma unroll
  for (int ks = 0; ks < 8; ++ks) {
    float4 a0 = *(const float4*)(ap + ks * 32);
    float4 a1 = *(const float4*)(ap + ks * 32 + 4);
    af[ks][0] = (half_t)a0.x; af[ks][1] = (half_t)a0.y;
    af[ks][2] = (half_t)a0.z; af[ks][3] = (half_t)a0.w;
    af[ks][4] = (half_t)a1.x; af[ks][5] = (half_t)a1.y;
    af[ks][6] = (half_t)a1.z; af[ks][7] = (half_t)a1.w;
  }
  f32x4 acc[4] = {};
#pragma unroll
  for (int ks = 0; ks < 8; ++ks) {
#pragma unroll
    for (int nt = 0; nt < 4; ++nt) {
      half8_t bf = *(const half8_t*)(btOp1 + ((((size_t)nt * 8 + ks) * 64 + lane) << 3));
      acc[nt] = __builtin_amdgcn_mfma_f32_16x16x32_f16(af[ks], bf, acc[nt], 0, 0, 0);
    }
  }
  int orow0 = blockIdx.x * 64 + w * 16 + kg * 4;
  float hrow[4][4];  // [row][nt]
#pragma unroll
  for (int nt = 0; nt < 4; ++nt) {
    float bv = b1[nt * 16 + r16];
#pragma unroll
    for (int r = 0; r < 4; ++r) hrow[r][nt] = fmaxf(acc[nt][r] + bv, 0.f);
  }
  float w2l[4][5];
#pragma unroll
  for (int nt = 0; nt < 4; ++nt)
#pragma unroll
    for (int o = 0; o < 5; ++o) w2l[nt][o] = W2[(nt * 16 + r16) * 5 + o];
#pragma unroll
  for (int r = 0; r < 4; ++r) {
    float y[5];
#pragma unroll
    for (int o = 0; o < 5; ++o) {
      float p = hrow[r][0] * w2l[0][o] + hrow[r][1] * w2l[1][o]
              + hrow[r][2] * w2l[2][o] + hrow[r][3] * w2l[3][o];
#pragma unroll
      for (int d = 1; d < 16; d <<= 1) p += __shfl_xor(p, d);
      y[o] = p + b2[o];
    }
    int grow = orow0 + r;
    if (r16 == 0 && grow < N) {
#pragma unroll
      for (int o = 0; o < 5; ++o) out[(size_t)grow * 5 + o] = y[o];
    }
  }
}

extern "C" void kernel_launch(void* const* d_in, const int* in_sizes, int n_in,
                              void* d_out, int out_size, void* d_ws, size_t ws_size,
                              hipStream_t stream) {
  const float* nf      = (const float*)d_in[0];
  const float* gf      = (const float*)d_in[1];
  const int*   eidx    = (const int*)d_in[2];
  const float* pos     = (const float*)d_in[3];
  const float* ip_W    = (const float*)d_in[4];
  const float* ip_b    = (const float*)d_in[5];
  const float* film_gW = (const float*)d_in[6];
  const float* film_gb = (const float*)d_in[7];
  const float* film_bW = (const float*)d_in[8];
  const float* film_bb = (const float*)d_in[9];
  const float* ee_W1   = (const float*)d_in[10];
  const float* ee_b1   = (const float*)d_in[11];
  const float* ee_W2   = (const float*)d_in[12];
  const float* ee_b2   = (const float*)d_in[13];
  const float* res_W   = (const float*)d_in[14];
  const float* res_b   = (const float*)d_in[15];
  const float* l0_Wl   = (const float*)d_in[16];
  const float* l0_bl   = (const float*)d_in[17];
  const float* l0_Wr   = (const float*)d_in[18];
  const float* l0_br   = (const float*)d_in[19];
  const float* Wl      = (const float*)d_in[20];
  const float* bl      = (const float*)d_in[21];
  const float* Wr      = (const float*)d_in[22];
  const float* br      = (const float*)d_in[23];
  const float* We      = (const float*)d_in[24];
  const float* att     = (const float*)d_in[25];
  const float* conv_b  = (const float*)d_in[26];
  const float* ln_g    = (const float*)d_in[27];
  const float* ln_b    = (const float*)d_in[28];
  const float* op_W1   = (const float*)d_in[29];
  const float* op_b1   = (const float*)d_in[30];
  const float* op_W2   = (const float*)d_in[31];
  const float* op_b2   = (const float*)d_in[32];

  const int N = in_sizes[0] / 5;
  const int E = in_sizes[2] / 2;
  const int* src = eidx;
  const int* dst = eidx + E;

  float* ws = (float*)d_ws;
  size_t o = 0;
  auto alloc = [&](size_t nflt) {
    float* p = ws + o;
    o += (nflt + 63) & ~(size_t)63;
    return p;
  };
  float* gbv     = alloc(128);
  float* x64     = alloc((size_t)N * 64);
  half_t* ef_csr = (half_t*)alloc((size_t)E * 16);   // E*32 halfs
  int*   src_csr = (int*)alloc((size_t)E);
  int*   dst_csr = (int*)alloc((size_t)E);
  int*   eid     = (int*)alloc((size_t)E);
  int*   cnt     = (int*)alloc(2 * (size_t)N + 64);  // [cnt N][cur N][cursor]
  int*   cur     = cnt + N;
  int*   cursor  = cnt + 2 * N;
  int*   csrst   = (int*)alloc((size_t)N);
  float* logits  = alloc((size_t)E * 4);
  half_t* xl     = (half_t*)alloc((size_t)N * 128);  // N*256 halfs
  half_t* xr     = (half_t*)alloc((size_t)N * 128);  // N*256 halfs
  float* xA      = alloc((size_t)N * 256);
  float* xB      = alloc((size_t)N * 256);
  half_t* btL0l  = (half_t*)alloc(256 * 64 / 2);
  half_t* btL0r  = (half_t*)alloc(256 * 64 / 2);
  half_t* btRes  = (half_t*)alloc(256 * 64 / 2);
  half_t* btWl   = (half_t*)alloc(5 * 256 * 256 / 2);
  half_t* btWr   = (half_t*)alloc(5 * 256 * 256 / 2);
  half_t* wet    = (half_t*)alloc(6 * 256 * 32 / 2);  // packed We fragments per layer
  half_t* btOp1  = (half_t*)alloc(64 * 256 / 2);      // packed op_W1 fragments

  (void)ws_size; (void)n_in; (void)out_size;

  hipMemsetAsync(cnt, 0, (2 * (size_t)N + 64) * sizeof(int), stream);

  const int nbN = (N + 255) / 256;
  const int nbE = (E + 255) / 256;
  k_film<<<1, 64, 0, stream>>>(gf, film_gW, film_gb, film_bW, film_bb, gbv);
  k_input<<<(N + 3) / 4, 256, 0, stream>>>(nf, ip_W, ip_b, gbv, x64, N);
  k_count<<<nbE, 256, 0, stream>>>(dst, cnt, E);
  k_offsets<<<nbN, 256, 0, stream>>>(cnt, csrst, cursor, N);
  k_scatter<<<nbE, 256, 0, stream>>>(dst, csrst, cur, eid, E);
  k_edgefeat<<<nbE, 256, 0, stream>>>(pos, src, dst, eid,
      ee_W1, ee_b1, ee_W2, ee_b2, ef_csr, src_csr, dst_csr, E);
  k_prepAll<<<dim3(256, 20), 256, 0, stream>>>(l0_Wl, l0_Wr, res_W, Wl, Wr, We, op_W1,
                                               btL0l, btL0r, btRes, btWl, btWr, wet, btOp1);

  const int gx = (N + 63) / 64;
  const int ge = (E + 63) / 64;
  const float* xin = x64;
  for (int layer = 0; layer < 6; ++layer) {
    const float* prev;
    if (layer == 0) {
      k_gemmL0<<<dim3(gx, 12), 256, 0, stream>>>(xin, btL0l, btL0r, btRes,
                                                 l0_bl, l0_br, res_b, xl, xr, xB, N);
      prev = xB;
    } else {
      k_gemmL<<<gx * 8, 256, 0, stream>>>(
          xin, btWl + (size_t)(layer - 1) * 65536, btWr + (size_t)(layer - 1) * 65536,
          bl + (size_t)(layer - 1) * 256, br + (size_t)(layer - 1) * 256, xl, xr, N);
      prev = xin;
    }

    k_elogits<<<ge, 256, 0, stream>>>(ef_csr, src_csr, dst_csr, xl, xr,
                                      wet + (size_t)layer * 256 * 32,
                                      att + (size_t)layer * 256, logits, E);

    float* xout = (layer & 1) ? xB : xA;
    k_fused<<<N, 64, 0, stream>>>(
        csrst, cnt, src_csr, logits, xl, prev,
        conv_b + (size_t)layer * 256, ln_g + (size_t)layer * 256, ln_b + (size_t)layer * 256,
        xout);
    xin = xout;
  }

  k_out2<<<gx, 256, 0, stream>>>(xin, btOp1, op_b1, op_W2, op_b2, (float*)d_out, N);
}

// Round 23
// 686.920 us; speedup vs baseline: 1.0142x; 1.0142x over previous
//
#include <hip/hip_runtime.h>
#include <cmath>

#define DEV static __device__ __forceinline__

typedef _Float16 half_t;
typedef _Float16 half2_t __attribute__((ext_vector_type(2)));
typedef _Float16 half4_t __attribute__((ext_vector_type(4)));
typedef _Float16 half8_t __attribute__((ext_vector_type(8)));
typedef float f32x4 __attribute__((ext_vector_type(4)));

// ---------------- FiLM: gamma/beta once ----------------
__global__ void k_film(const float* __restrict__ gf,
                       const float* __restrict__ gW, const float* __restrict__ gb,
                       const float* __restrict__ bW, const float* __restrict__ bb,
                       float* __restrict__ out) {
  int j = threadIdx.x;
  if (j >= 64) return;
  float g = gb[j], b = bb[j];
  for (int k = 0; k < 128; ++k) {
    float v = gf[k];
    g += v * gW[k * 64 + j];
    b += v * bW[k * 64 + j];
  }
  out[j] = 1.0f + g;
  out[64 + j] = b;
}

// ---------------- input projection + FiLM (gamma/beta precomputed) ----------------
__global__ __launch_bounds__(256) void k_input(
    const float* __restrict__ nf, const float* __restrict__ ipW,
    const float* __restrict__ ipb, const float* __restrict__ gbv,
    float* __restrict__ x64, int N) {
  int lane = threadIdx.x & 63;
  int n = blockIdx.x * 4 + (threadIdx.x >> 6);
  if (n >= N) return;
  const float* row = nf + (size_t)n * 5;
  float acc = ipb[lane];
#pragma unroll
  for (int k = 0; k < 5; ++k) acc += row[k] * ipW[k * 64 + lane];
  acc = fmaxf(acc, 0.f);
  x64[(size_t)n * 64 + lane] = acc * gbv[lane] + gbv[64 + lane];
}

// ---------------- CSR build ----------------
__global__ void k_count(const int* __restrict__ dst, int* __restrict__ cnt, int E) {
  int e = blockIdx.x * 256 + threadIdx.x;
  if (e < E) atomicAdd(&cnt[dst[e]], 1);
}

__global__ void k_offsets(const int* __restrict__ cnt, int* __restrict__ start,
                          int* __restrict__ cursor, int N) {
  __shared__ int s[256];
  __shared__ int sbase;
  int tid = threadIdx.x;
  int i = blockIdx.x * 256 + tid;
  int v = (i < N) ? cnt[i] : 0;
  s[tid] = v;
  __syncthreads();
  int x = v;
  for (int d = 1; d < 256; d <<= 1) {
    int t = (tid >= d) ? s[tid - d] : 0;
    __syncthreads();
    x += t;
    s[tid] = x;
    __syncthreads();
  }
  if (tid == 255) sbase = atomicAdd(cursor, x);
  __syncthreads();
  if (i < N) start[i] = sbase + x - v;
}

// ---------------- edge encoder + scatter fused (also records dst_csr) ----------------
__global__ __launch_bounds__(256) void k_edgefeat(
    const float* __restrict__ pos, const int* __restrict__ src, const int* __restrict__ dst,
    const int* __restrict__ start, int* __restrict__ cur,
    const float* __restrict__ W1, const float* __restrict__ b1,
    const float* __restrict__ W2, const float* __restrict__ b2,
    half_t* __restrict__ ef_csr, int* __restrict__ src_csr, int* __restrict__ dst_csr, int E) {
  __shared__ float sW1[160], sb1[32], sW2[1024], sb2[32];
  for (int i = threadIdx.x; i < 160; i += 256) sW1[i] = W1[i];
  for (int i = threadIdx.x; i < 1024; i += 256) sW2[i] = W2[i];
  if (threadIdx.x < 32) { sb1[threadIdx.x] = b1[threadIdx.x]; sb2[threadIdx.x] = b2[threadIdx.x]; }
  __syncthreads();
  int e = blockIdx.x * 256 + threadIdx.x;
  if (e >= E) return;
  int s = src[e], d = dst[e];
  int p = atomicAdd(&cur[d], 1);
  int t = start[d] + p;
  src_csr[t] = s;
  dst_csr[t] = d;
  float dx = pos[d * 3 + 0] - pos[s * 3 + 0];
  float dy = pos[d * 3 + 1] - pos[s * 3 + 1];
  float dz = pos[d * 3 + 2] - pos[s * 3 + 2];
  float dist = sqrtf(dx * dx + dy * dy + dz * dz);
  dist = fmaxf(dist, 1e-6f);
  float inv = 1.f / dist;
  float attr[5] = {dx * inv, dy * inv, dz * inv, dist, logf(dist)};
  float h[32];
#pragma unroll
  for (int j = 0; j < 32; ++j) {
    float a = sb1[j];
#pragma unroll
    for (int k = 0; k < 5; ++k) a += attr[k] * sW1[k * 32 + j];
    h[j] = fmaxf(a, 0.f);
  }
  half_t hv[32];
#pragma unroll 4
  for (int j = 0; j < 32; ++j) {
    float a = sb2[j];
#pragma unroll
    for (int k = 0; k < 32; ++k) a += h[k] * sW2[k * 32 + j];
    hv[j] = (half_t)a;
  }
  uint4* ov = (uint4*)(ef_csr + (size_t)t * 32);
  const uint4* iv = (const uint4*)hv;
  ov[0] = iv[0]; ov[1] = iv[1]; ov[2] = iv[2]; ov[3] = iv[3];
}

// ---------------- batched weight prep: MFMA-fragment-ordered f16 packing ----------------
__global__ __launch_bounds__(256) void k_prepAll(
    const float* __restrict__ l0Wl, const float* __restrict__ l0Wr,
    const float* __restrict__ resW, const float* __restrict__ Wl,
    const float* __restrict__ Wr, const float* __restrict__ We,
    const float* __restrict__ opW1,
    half_t* __restrict__ btL0l, half_t* __restrict__ btL0r, half_t* __restrict__ btRes,
    half_t* __restrict__ btWl, half_t* __restrict__ btWr, half_t* __restrict__ wet,
    half_t* __restrict__ btOp1) {
  int m = blockIdx.y;
  const float* W;
  half_t* Bt;
  int K, ncol;
  if (m == 0)      { W = l0Wl; Bt = btL0l; K = 64;  ncol = 256; }
  else if (m == 1) { W = l0Wr; Bt = btL0r; K = 64;  ncol = 256; }
  else if (m == 2) { W = resW; Bt = btRes; K = 64;  ncol = 256; }
  else if (m < 8)  { int i = m - 3;  W = Wl + (size_t)i * 65536; Bt = btWl + (size_t)i * 65536; K = 256; ncol = 256; }
  else if (m < 13) { int i = m - 8;  W = Wr + (size_t)i * 65536; Bt = btWr + (size_t)i * 65536; K = 256; ncol = 256; }
  else if (m < 19) { int i = m - 13; W = We + (size_t)i * 8192;  Bt = wet + (size_t)i * 8192;  K = 32;  ncol = 256; }
  else             { W = opW1; Bt = btOp1; K = 256; ncol = 64; }
  int KS = K >> 5;
  int tot = K * ncol;
  int i = blockIdx.x * 256 + threadIdx.x;
  if (i < tot) {
    int jj = i & 7;
    int lane = (i >> 3) & 63;
    int rest = i >> 9;
    int ks = rest % KS;
    int c16 = rest / KS;
    int k = ks * 32 + (lane >> 4) * 8 + jj;
    int col = c16 * 16 + (lane & 15);
    Bt[i] = (half_t)W[(size_t)k * ncol + col];
  }
}

// ---------------- MFMA f16 GEMM, 64x64 tile per block, fragment-packed B ----------------
template <typename OutT, int NKS>
DEV void gemm_tile(const float* __restrict__ A, const half_t* __restrict__ Bf,
                   const float* __restrict__ bias, OutT* __restrict__ C,
                   int M, int bx, int bcol, int tid) {
  constexpr int K = NKS * 32;
  int w = tid >> 6, lane = tid & 63;
  int r16 = lane & 15, kg = lane >> 4;
  int arow = bx * 64 + w * 16 + r16;
  int arowc = arow < M ? arow : M - 1;
  const float* ap = A + (size_t)arowc * K + kg * 8;
  int c16b = bcol >> 4;
  f32x4 acc[4] = {};
#pragma unroll
  for (int ks = 0; ks < NKS; ++ks) {
    float4 a0 = *(const float4*)(ap + ks * 32);
    float4 a1 = *(const float4*)(ap + ks * 32 + 4);
    half8_t af;
    af[0] = (half_t)a0.x; af[1] = (half_t)a0.y; af[2] = (half_t)a0.z; af[3] = (half_t)a0.w;
    af[4] = (half_t)a1.x; af[5] = (half_t)a1.y; af[6] = (half_t)a1.z; af[7] = (half_t)a1.w;
#pragma unroll
    for (int nt = 0; nt < 4; ++nt) {
      half8_t bf = *(const half8_t*)(Bf + ((((size_t)(c16b + nt) * NKS + ks) * 64 + lane) << 3));
      acc[nt] = __builtin_amdgcn_mfma_f32_16x16x32_f16(af, bf, acc[nt], 0, 0, 0);
    }
  }
  int orow0 = bx * 64 + w * 16 + kg * 4;
#pragma unroll
  for (int nt = 0; nt < 4; ++nt) {
    int gcol = bcol + nt * 16 + r16;
    float bv = bias[gcol];
#pragma unroll
    for (int r = 0; r < 4; ++r) {
      int grow = orow0 + r;
      if (grow < M) C[(size_t)grow * 256 + gcol] = (OutT)(acc[nt][r] + bv);
    }
  }
}

// layers 1..5 (K=256): 1D grid (gx*8), XCD-swizzled (8 tiles of one bx -> same XCD chunk)
__global__ __launch_bounds__(256) void k_gemmL(
    const float* __restrict__ A, const half_t* __restrict__ btl,
    const half_t* __restrict__ btr, const float* __restrict__ bl,
    const float* __restrict__ br, half_t* __restrict__ xl, half_t* __restrict__ xr, int M) {
  int nwg = gridDim.x;
  int cpx = nwg >> 3;
  int orig = blockIdx.x;
  int bid = (orig & 7) * cpx + (orig >> 3);
  int bx = bid >> 3, yt = bid & 7;
  if (yt < 4)
    gemm_tile<half_t, 8>(A, btl, bl, xl, M, bx, yt * 64, threadIdx.x);
  else
    gemm_tile<half_t, 8>(A, btr, br, xr, M, bx, (yt - 4) * 64, threadIdx.x);
}

// layer 0 (K=64)
__global__ __launch_bounds__(256) void k_gemmL0(
    const float* __restrict__ A, const half_t* __restrict__ btl,
    const half_t* __restrict__ btr, const half_t* __restrict__ btres,
    const float* __restrict__ bl, const float* __restrict__ br,
    const float* __restrict__ bres,
    half_t* __restrict__ xl, half_t* __restrict__ xr, float* __restrict__ xres, int M) {
  if (blockIdx.y < 4)
    gemm_tile<half_t, 2>(A, btl, bl, xl, M, blockIdx.x, blockIdx.y * 64, threadIdx.x);
  else if (blockIdx.y < 8)
    gemm_tile<half_t, 2>(A, btr, br, xr, M, blockIdx.x, (blockIdx.y - 4) * 64, threadIdx.x);
  else
    gemm_tile<float, 2>(A, btres, bres, xres, M, blockIdx.x, (blockIdx.y - 8) * 64, threadIdx.x);
}

// ---------------- edge-parallel gate weights: MFMA ef@We (fragment-packed, MLP-hoisted) ----------------
__global__ __launch_bounds__(256) void k_elogits(
    const half_t* __restrict__ ef_csr, const int* __restrict__ src_csr,
    const int* __restrict__ dst_csr, const half_t* __restrict__ xl,
    const half_t* __restrict__ xr, const half_t* __restrict__ wetf,
    const float* __restrict__ att_l, float* __restrict__ logits, int E) {
  int tid = threadIdx.x;
  int w = tid >> 6, lane = tid & 63;
  int r16 = lane & 15, kg = lane >> 4;
  int arow = blockIdx.x * 64 + w * 16 + r16;
  int arowc = arow < E ? arow : E - 1;
  half8_t af = *(const half8_t*)(ef_csr + (size_t)arowc * 32 + kg * 8);
  half8_t bfv[16];
#pragma unroll
  for (int nt = 0; nt < 16; ++nt)
    bfv[nt] = *(const half8_t*)(wetf + (((size_t)nt * 64 + lane) << 3));
  int orow0 = blockIdx.x * 64 + w * 16 + kg * 4;
  int s_[4], d_[4];
#pragma unroll
  for (int r = 0; r < 4; ++r) {
    int tt = orow0 + r;
    tt = tt < E ? tt : E - 1;
    s_[r] = src_csr[tt];
    d_[r] = dst_csr[tt];
  }
  float latt[4][4] = {};  // [head][row]
#pragma unroll
  for (int nt = 0; nt < 16; ++nt) {
    int col = nt * 16 + r16;
    f32x4 dacc = {};
    dacc = __builtin_amdgcn_mfma_f32_16x16x32_f16(af, bfv[nt], dacc, 0, 0, 0);
    float attc = att_l[col];
    float a06 = 0.6f * attc, a04 = 0.4f * attc;
    int hh = nt >> 2;
#pragma unroll
    for (int r = 0; r < 4; ++r) {
      float z = dacc[r] + (float)(xl[(size_t)s_[r] * 256 + col] + xr[(size_t)d_[r] * 256 + col]);
      latt[hh][r] += a06 * z + a04 * fabsf(z);
    }
  }
#pragma unroll
  for (int d = 1; d < 16; d <<= 1) {
#pragma unroll
    for (int hh = 0; hh < 4; ++hh)
#pragma unroll
      for (int r = 0; r < 4; ++r) latt[hh][r] += __shfl_xor(latt[hh][r], d);
  }
  if (r16 == 0) {
#pragma unroll
    for (int r = 0; r < 4; ++r) {
      int tt = orow0 + r;
      if (tt < E) {
        float4 lv = {__expf(latt[0][r]), __expf(latt[1][r]),
                     __expf(latt[2][r]), __expf(latt[3][r])};
        *(float4*)(logits + (size_t)tt * 4) = lv;
      }
    }
  }
}

// ---------------- fused softmax-aggregate + conv_b + LN + relu + residual ----------------
__global__ __launch_bounds__(64) void k_fused(
    const int* __restrict__ start, const int* __restrict__ cnt,
    const int* __restrict__ src_csr, const float* __restrict__ logits,
    const half_t* __restrict__ xl, const float* __restrict__ xprev,
    const float* __restrict__ convb, const float* __restrict__ lng,
    const float* __restrict__ lnb,
    float* __restrict__ xout) {
  int lane = threadIdx.x;
  int n = blockIdx.x;
  int h = lane >> 4, c0 = lane & 15;
  int ch0 = h * 64 + (c0 << 2);
  float4 cb4 = *(const float4*)(convb + ch0);
  float4 g4 = *(const float4*)(lng + ch0);
  float4 b4 = *(const float4*)(lnb + ch0);
  int o0 = start[n];
  int deg = cnt[n];
  int o1 = o0 + deg;
  float s = 0.f;
  float4 a4 = {0.f, 0.f, 0.f, 0.f};

#define LOADG(T0, X0, X1, X2, X3, L0, L1, L2, L3)                                    \
  {                                                                                  \
    int lim = o1 - 1;                                                                \
    int t0_ = (T0) < lim ? (T0) : lim;                                               \
    int t1_ = (T0) + 1 < lim ? (T0) + 1 : lim;                                       \
    int t2_ = (T0) + 2 < lim ? (T0) + 2 : lim;                                       \
    int t3_ = (T0) + 3 < lim ? (T0) + 3 : lim;                                       \
    int S0 = src_csr[t0_], S1 = src_csr[t1_], S2 = src_csr[t2_], S3 = src_csr[t3_];  \
    X0 = *(const half4_t*)(xl + (size_t)S0 * 256 + ch0);                             \
    X1 = *(const half4_t*)(xl + (size_t)S1 * 256 + ch0);                             \
    X2 = *(const half4_t*)(xl + (size_t)S2 * 256 + ch0);                             \
    X3 = *(const half4_t*)(xl + (size_t)S3 * 256 + ch0);                             \
    L0 = logits[(size_t)t0_ * 4 + h];                                                \
    L1 = logits[(size_t)t1_ * 4 + h];                                                \
    L2 = logits[(size_t)t2_ * 4 + h];                                                \
    L3 = logits[(size_t)t3_ * 4 + h];                                                \
  }

#define CVT4(XH, XF)                                                                 \
  float4 XF;                                                                         \
  XF.x = (float)(XH)[0]; XF.y = (float)(XH)[1];                                      \
  XF.z = (float)(XH)[2]; XF.w = (float)(XH)[3];

  if (deg > 0) {
    int nfull = deg >> 2;
    half4_t xh0, xh1, xh2, xh3;
    float l0, l1, l2, l3;
    LOADG(o0, xh0, xh1, xh2, xh3, l0, l1, l2, l3);
    int t0 = o0;
    for (int g = 0; g < nfull; ++g, t0 += 4) {
      half4_t nxh0, nxh1, nxh2, nxh3;
      float nl0, nl1, nl2, nl3;
      LOADG(t0 + 4, nxh0, nxh1, nxh2, nxh3, nl0, nl1, nl2, nl3);
      CVT4(xh0, xf0); CVT4(xh1, xf1); CVT4(xh2, xf2); CVT4(xh3, xf3);
      s += (l0 + l1) + (l2 + l3);
      a4.x += l0 * xf0.x + l1 * xf1.x + l2 * xf2.x + l3 * xf3.x;
      a4.y += l0 * xf0.y + l1 * xf1.y + l2 * xf2.y + l3 * xf3.y;
      a4.z += l0 * xf0.z + l1 * xf1.z + l2 * xf2.z + l3 * xf3.z;
      a4.w += l0 * xf0.w + l1 * xf1.w + l2 * xf2.w + l3 * xf3.w;
      xh0 = nxh0; xh1 = nxh1; xh2 = nxh2; xh3 = nxh3;
      l0 = nl0; l1 = nl1; l2 = nl2; l3 = nl3;
    }
    int r = deg & 3;
    if (r) {
      CVT4(xh0, xf0); CVT4(xh1, xf1); CVT4(xh2, xf2);
      float w0 = l0;
      float w1 = (r > 1) ? l1 : 0.f;
      float w2v = (r > 2) ? l2 : 0.f;
      s += w0 + w1 + w2v;
      a4.x += w0 * xf0.x + w1 * xf1.x + w2v * xf2.x;
      a4.y += w0 * xf0.y + w1 * xf1.y + w2v * xf2.y;
      a4.z += w0 * xf0.z + w1 * xf1.z + w2v * xf2.z;
      a4.w += w0 * xf0.w + w1 * xf1.w + w2v * xf2.w;
    }
  }
#undef CVT4
#undef LOADG

  float inv = (deg > 0) ? 1.f / s : 0.f;
  float4 v4;
  v4.x = a4.x * inv + cb4.x;
  v4.y = a4.y * inv + cb4.y;
  v4.z = a4.z * inv + cb4.z;
  v4.w = a4.w * inv + cb4.w;
  float ssum = v4.x + v4.y + v4.z + v4.w;
  float ssq = v4.x * v4.x + v4.y * v4.y + v4.z * v4.z + v4.w * v4.w;
#pragma unroll
  for (int d = 1; d < 64; d <<= 1) {
    ssum += __shfl_xor(ssum, d);
    ssq += __shfl_xor(ssq, d);
  }
  float mu = ssum * (1.0f / 256.0f);
  float var = ssq * (1.0f / 256.0f) - mu * mu;
  float rstd = rsqrtf(var + 1e-5f);
  float4 xp4 = *(const float4*)(xprev + (size_t)n * 256 + ch0);
  float4 out4;
  out4.x = fmaxf((v4.x - mu) * rstd * g4.x + b4.x, 0.f) + xp4.x;
  out4.y = fmaxf((v4.y - mu) * rstd * g4.y + b4.y, 0.f) + xp4.y;
  out4.z = fmaxf((v4.z - mu) * rstd * g4.z + b4.z, 0.f) + xp4.z;
  out4.w = fmaxf((v4.w - mu) * rstd * g4.w + b4.w, 0.f) + xp4.w;
  *(float4*)(xout + (size_t)n * 256 + ch0) = out4;
}

// ---------------- output projection: MFMA stage1 (256->64, packed B) + stage2 (64->5) ----------------
__global__ __launch_bounds__(256) void k_out2(
    const float* __restrict__ x, const half_t* __restrict__ btOp1,
    const float* __restrict__ b1, const float* __restrict__ W2,
    const float* __restrict__ b2, float* __restrict__ out, int N) {
  int tid = threadIdx.x;
  int w = tid >> 6, lane = tid & 63;
  int r16 = lane & 15, kg = lane >> 4;
  int arow = blockIdx.x * 64 + w * 16 + r16;
  int arowc = arow < N ? arow : N - 1;
  const float* ap = x + (size_t)arowc * 256 + kg * 8;
  half8_t af[8];
#pragma unroll
  for (int ks = 0; ks < 8; ++ks) {
    float4 a0 = *(const float4*)(ap + ks * 32);
    float4 a1 = *(const float4*)(ap + ks * 32 + 4);
    af[ks][0] = (half_t)a0.x; af[ks][1] = (half_t)a0.y;
    af[ks][2] = (half_t)a0.z; af[ks][3] = (half_t)a0.w;
    af[ks][4] = (half_t)a1.x; af[ks][5] = (half_t)a1.y;
    af[ks][6] = (half_t)a1.z; af[ks][7] = (half_t)a1.w;
  }
  f32x4 acc[4] = {};
#pragma unroll
  for (int ks = 0; ks < 8; ++ks) {
#pragma unroll
    for (int nt = 0; nt < 4; ++nt) {
      half8_t bf = *(const half8_t*)(btOp1 + ((((size_t)nt * 8 + ks) * 64 + lane) << 3));
      acc[nt] = __builtin_amdgcn_mfma_f32_16x16x32_f16(af[ks], bf, acc[nt], 0, 0, 0);
    }
  }
  int orow0 = blockIdx.x * 64 + w * 16 + kg * 4;
  float hrow[4][4];  // [row][nt]
#pragma unroll
  for (int nt = 0; nt < 4; ++nt) {
    float bv = b1[nt * 16 + r16];
#pragma unroll
    for (int r = 0; r < 4; ++r) hrow[r][nt] = fmaxf(acc[nt][r] + bv, 0.f);
  }
  float w2l[4][5];
#pragma unroll
  for (int nt = 0; nt < 4; ++nt)
#pragma unroll
    for (int o = 0; o < 5; ++o) w2l[nt][o] = W2[(nt * 16 + r16) * 5 + o];
#pragma unroll
  for (int r = 0; r < 4; ++r) {
    float y[5];
#pragma unroll
    for (int o = 0; o < 5; ++o) {
      float p = hrow[r][0] * w2l[0][o] + hrow[r][1] * w2l[1][o]
              + hrow[r][2] * w2l[2][o] + hrow[r][3] * w2l[3][o];
#pragma unroll
      for (int d = 1; d < 16; d <<= 1) p += __shfl_xor(p, d);
      y[o] = p + b2[o];
    }
    int grow = orow0 + r;
    if (r16 == 0 && grow < N) {
#pragma unroll
      for (int o = 0; o < 5; ++o) out[(size_t)grow * 5 + o] = y[o];
    }
  }
}

extern "C" void kernel_launch(void* const* d_in, const int* in_sizes, int n_in,
                              void* d_out, int out_size, void* d_ws, size_t ws_size,
                              hipStream_t stream) {
  const float* nf      = (const float*)d_in[0];
  const float* gf      = (const float*)d_in[1];
  const int*   eidx    = (const int*)d_in[2];
  const float* pos     = (const float*)d_in[3];
  const float* ip_W    = (const float*)d_in[4];
  const float* ip_b    = (const float*)d_in[5];
  const float* film_gW = (const float*)d_in[6];
  const float* film_gb = (const float*)d_in[7];
  const float* film_bW = (const float*)d_in[8];
  const float* film_bb = (const float*)d_in[9];
  const float* ee_W1   = (const float*)d_in[10];
  const float* ee_b1   = (const float*)d_in[11];
  const float* ee_W2   = (const float*)d_in[12];
  const float* ee_b2   = (const float*)d_in[13];
  const float* res_W   = (const float*)d_in[14];
  const float* res_b   = (const float*)d_in[15];
  const float* l0_Wl   = (const float*)d_in[16];
  const float* l0_bl   = (const float*)d_in[17];
  const float* l0_Wr   = (const float*)d_in[18];
  const float* l0_br   = (const float*)d_in[19];
  const float* Wl      = (const float*)d_in[20];
  const float* bl      = (const float*)d_in[21];
  const float* Wr      = (const float*)d_in[22];
  const float* br      = (const float*)d_in[23];
  const float* We      = (const float*)d_in[24];
  const float* att     = (const float*)d_in[25];
  const float* conv_b  = (const float*)d_in[26];
  const float* ln_g    = (const float*)d_in[27];
  const float* ln_b    = (const float*)d_in[28];
  const float* op_W1   = (const float*)d_in[29];
  const float* op_b1   = (const float*)d_in[30];
  const float* op_W2   = (const float*)d_in[31];
  const float* op_b2   = (const float*)d_in[32];

  const int N = in_sizes[0] / 5;
  const int E = in_sizes[2] / 2;
  const int* src = eidx;
  const int* dst = eidx + E;

  float* ws = (float*)d_ws;
  size_t o = 0;
  auto alloc = [&](size_t nflt) {
    float* p = ws + o;
    o += (nflt + 63) & ~(size_t)63;
    return p;
  };
  float* gbv     = alloc(128);
  float* x64     = alloc((size_t)N * 64);
  half_t* ef_csr = (half_t*)alloc((size_t)E * 16);   // E*32 halfs
  int*   src_csr = (int*)alloc((size_t)E);
  int*   dst_csr = (int*)alloc((size_t)E);
  int*   cnt     = (int*)alloc(2 * (size_t)N + 64);  // [cnt N][cur N][cursor]
  int*   cur     = cnt + N;
  int*   cursor  = cnt + 2 * N;
  int*   csrst   = (int*)alloc((size_t)N);
  float* logits  = alloc((size_t)E * 4);
  half_t* xl     = (half_t*)alloc((size_t)N * 128);  // N*256 halfs
  half_t* xr     = (half_t*)alloc((size_t)N * 128);  // N*256 halfs
  float* xA      = alloc((size_t)N * 256);
  float* xB      = alloc((size_t)N * 256);
  half_t* btL0l  = (half_t*)alloc(256 * 64 / 2);
  half_t* btL0r  = (half_t*)alloc(256 * 64 / 2);
  half_t* btRes  = (half_t*)alloc(256 * 64 / 2);
  half_t* btWl   = (half_t*)alloc(5 * 256 * 256 / 2);
  half_t* btWr   = (half_t*)alloc(5 * 256 * 256 / 2);
  half_t* wet    = (half_t*)alloc(6 * 256 * 32 / 2);  // packed We fragments per layer
  half_t* btOp1  = (half_t*)alloc(64 * 256 / 2);      // packed op_W1 fragments

  (void)ws_size; (void)n_in; (void)out_size;

  hipMemsetAsync(cnt, 0, (2 * (size_t)N + 64) * sizeof(int), stream);

  const int nbN = (N + 255) / 256;
  k_film<<<1, 64, 0, stream>>>(gf, film_gW, film_gb, film_bW, film_bb, gbv);
  k_input<<<(N + 3) / 4, 256, 0, stream>>>(nf, ip_W, ip_b, gbv, x64, N);
  k_count<<<(E + 255) / 256, 256, 0, stream>>>(dst, cnt, E);
  k_offsets<<<nbN, 256, 0, stream>>>(cnt, csrst, cursor, N);
  k_edgefeat<<<(E + 255) / 256, 256, 0, stream>>>(pos, src, dst, csrst, cur,
      ee_W1, ee_b1, ee_W2, ee_b2, ef_csr, src_csr, dst_csr, E);
  k_prepAll<<<dim3(256, 20), 256, 0, stream>>>(l0_Wl, l0_Wr, res_W, Wl, Wr, We, op_W1,
                                               btL0l, btL0r, btRes, btWl, btWr, wet, btOp1);

  const int gx = (N + 63) / 64;
  const int ge = (E + 63) / 64;
  const float* xin = x64;
  for (int layer = 0; layer < 6; ++layer) {
    const float* prev;
    if (layer == 0) {
      k_gemmL0<<<dim3(gx, 12), 256, 0, stream>>>(xin, btL0l, btL0r, btRes,
                                                 l0_bl, l0_br, res_b, xl, xr, xB, N);
      prev = xB;
    } else {
      k_gemmL<<<gx * 8, 256, 0, stream>>>(
          xin, btWl + (size_t)(layer - 1) * 65536, btWr + (size_t)(layer - 1) * 65536,
          bl + (size_t)(layer - 1) * 256, br + (size_t)(layer - 1) * 256, xl, xr, N);
      prev = xin;
    }

    k_elogits<<<ge, 256, 0, stream>>>(ef_csr, src_csr, dst_csr, xl, xr,
                                      wet + (size_t)layer * 256 * 32,
                                      att + (size_t)layer * 256, logits, E);

    float* xout = (layer & 1) ? xB : xA;
    k_fused<<<N, 64, 0, stream>>>(
        csrst, cnt, src_csr, logits, xl, prev,
        conv_b + (size_t)layer * 256, ln_g + (size_t)layer * 256, ln_b + (size_t)layer * 256,
        xout);
    xin = xout;
  }

  k_out2<<<gx, 256, 0, stream>>>(xin, btOp1, op_b1, op_W2, op_b2, (float*)d_out, N);
}